// Round 17
// baseline (209.672 us; speedup 1.0000x reference)
//
#include <hip/hip_runtime.h>
#include <stdint.h>

#define S_ 8
#define N_ 4096
#define I_ 256
#define L_ 512
#define M_ 256
#define D_ 768   // I + L
#define NT64 12  // 768/64 K-tiles

typedef __bf16 bf16x8 __attribute__((ext_vector_type(8)));
typedef float f32x4 __attribute__((ext_vector_type(4)));
typedef unsigned short ushort_t;

__device__ __forceinline__ unsigned short f2bf(float f) {
  union { float f; uint32_t u; } c; c.f = f;
  uint32_t u = c.u;
  uint32_t r = u + 0x7FFFu + ((u >> 16) & 1u);
  return (unsigned short)(r >> 16);
}

__device__ __forceinline__ float fsigmoid(float x) {
  return 1.0f / (1.0f + __expf(-x));
}
__device__ __forceinline__ float ftanh(float x) {
  float ax = fabsf(x);
  float e = __expf(-2.0f * ax);
  float t = (1.0f - e) / (1.0f + e);
  return copysignf(t, x);
}

#define GLD16(gsrc, ldst)                                                                  \
  __builtin_amdgcn_global_load_lds(                                                        \
      (const __attribute__((address_space(1))) uint32_t*)(uintptr_t)(gsrc),                \
      (__attribute__((address_space(3))) uint32_t*)(uintptr_t)(ldst), 16, 0, 0)

// ---------------- fused prep kernel (verified r13-r16) ----------------
__global__ __launch_bounds__(256) void prep_kernel(
    const float* __restrict__ mod, const float* __restrict__ h0,
    const float* __restrict__ Wi, const float* __restrict__ Wf,
    const float* __restrict__ Wg, const float* __restrict__ Wo,
    const float* __restrict__ Wy, ushort_t* __restrict__ w4,
    ushort_t* __restrict__ wyb, ushort_t* __restrict__ xh) {
  const int y = blockIdx.y;
  int t = blockIdx.x * 256 + threadIdx.x;
  const int stride = gridDim.x * 256;
  if (y < 4) {
    const float* src = (y == 0) ? Wi : (y == 1) ? Wf : (y == 2) ? Wg : Wo;
    ushort_t* dst = w4 + (size_t)y * S_ * L_ * D_;
    const int n4 = S_ * L_ * D_ / 4;
    for (; t < n4; t += stride) {
      float4 v = ((const float4*)src)[t];
      ushort4 o;
      o.x = f2bf(v.x); o.y = f2bf(v.y); o.z = f2bf(v.z); o.w = f2bf(v.w);
      ((ushort4*)dst)[t] = o;
    }
  } else if (y == 4) {
    const int n4 = S_ * M_ * L_ / 4;
    for (; t < n4; t += stride) {
      float4 v = ((const float4*)Wy)[t];
      ushort4 o;
      o.x = f2bf(v.x); o.y = f2bf(v.y); o.z = f2bf(v.z); o.w = f2bf(v.w);
      ((ushort4*)wyb)[t] = o;
    }
  } else if (y == 5) {
    const int total = S_ * N_ * (I_ / 4);
    for (; t < total; t += stride) {
      int r = t >> 6, c = t & 63;
      int s = r >> 12, n = r & (N_ - 1);
      float4 v = *(const float4*)(mod + (size_t)n * (S_ * I_) + s * I_ + c * 4);
      ushort4 o;
      o.x = f2bf(v.x); o.y = f2bf(v.y); o.z = f2bf(v.z); o.w = f2bf(v.w);
      *(ushort4*)(xh + (size_t)r * D_ + c * 4) = o;
    }
  } else {
    const int total = S_ * N_ * (L_ / 4);
    for (; t < total; t += stride) {
      int r = t >> 7, c = t & 127;
      int s = r >> 12, n = r & (N_ - 1);
      float4 v = *(const float4*)(h0 + (size_t)n * (S_ * L_) + s * L_ + c * 4);
      ushort4 o;
      o.x = f2bf(v.x); o.y = f2bf(v.y); o.z = f2bf(v.z); o.w = f2bf(v.w);
      *(ushort4*)(xh + (size_t)r * D_ + I_ + c * 4) = o;
    }
  }
}

// ---------------- gates r17: register-dbuf fragments — reads(s+1) overlap MFMA(s) ----------------
// 512 thr, 8 waves (wm=w>>2 -> 128 n-rows, wl=w&3 -> 16 l-cols), tile 256n x (4g x 64l).
// acc[8][4] lane-local (r6/r9-verified epilogue). BK=64, 2 kk-steps/tile. LDS 128 KB dbuf.
// Two fragment sets (a0/b0, a1/b1): each kk-step issues the NEXT step's 12 ds_reads into
// the alternate set, then runs 32 MFMAs on the current set (no mutual dependency ->
// in-order wave issue lets the LDS pipe drain under the MFMA burst). lgkm0 at step end
// is hidden. Per tile: stepA; lgkm0; bar; STAGE(t+2); vmcnt(8); bar; stepB; lgkm0.
// WAR-safe: all tile-t frags are in regs (lgkm0+bar) before STAGE(t+2) overwrites buf(t).
// vmcnt(8): exactly stage(t+1)'s 8 loads retired (8 gld/STAGE, 1 STAGE outstanding after issue).
__global__ __launch_bounds__(512, 2) void gates_kernel(
    const ushort_t* __restrict__ xh,   // [S][N][D] bf16
    const ushort_t* __restrict__ w4,   // [4][S][L][D] bf16
    const float* __restrict__ bi, const float* __restrict__ bff,
    const float* __restrict__ bg, const float* __restrict__ bo,
    const float* __restrict__ c0,      // [N][S*L] f32
    ushort_t* __restrict__ hout)       // [S][N][L] bf16
{
  __shared__ __align__(16) ushort_t smem[65536];  // 128 KB = 2 x 64 KB bufs {A 32K | B 32K}
  const int tid = threadIdx.x;
  const int lane = tid & 63;
  const int ln15 = lane & 15;
  const int ln4 = lane >> 4;
  const int w = tid >> 6;             // 0..7
  const int wm = w >> 2;              // 0..1 -> 128 n-rows
  const int wl = w & 3;               // 0..3 -> 16 l-cols

  const int bid = blockIdx.x;
  const int s = bid & 7;              // stream-per-XCD
  const int r = bid >> 3;             // 0..127
  const int n0 = (r >> 3) << 8;
  const int l0 = (r & 7) << 6;

  const size_t xh_base = (size_t)(s * N_ + n0) * D_;

  // staging decode (r1-native swizzle, r13-verified): 4 rounds of 512 slots each for A and B
  const ushort_t* aSrc[4];
  const ushort_t* bSrc[4];
  #pragma unroll
  for (int rd = 0; rd < 4; ++rd) {
    int slot = tid + (rd << 9);
    int row = slot >> 3;
    int cg = (slot & 7) ^ (row & 7);
    aSrc[rd] = xh + xh_base + (size_t)row * D_ + (cg << 3);
    int g = row >> 6, ll = row & 63;
    bSrc[rd] = w4 + ((size_t)((g * S_ + s) * L_) + l0 + ll) * D_ + (cg << 3);
  }

  // STAGE: 8 GLD16/thread (A 4 rounds + B 4 rounds). bs = buf slot base (0 or 4096).
#define STAGE(bs, tile) do {                                                            \
    const int k0_ = (tile) << 6;                                                        \
    _Pragma("unroll")                                                                   \
    for (int rd_ = 0; rd_ < 4; ++rd_) {                                                 \
      GLD16(aSrc[rd_] + k0_, &smem[((bs) + (rd_ << 9) + (w << 6)) * 8]);                \
      GLD16(bSrc[rd_] + k0_, &smem[((bs) + 2048 + (rd_ << 9) + (w << 6)) * 8]);         \
    }                                                                                   \
  } while (0)

  // ds_read byte bases (r16 scheme): row&7 == ln15&7 for all rt/g -> XOR folds into base
  const char* smemB = (const char*)smem;
  const uint32_t chk0 = (uint32_t)((ln4 ^ (ln15 & 7)) << 4);
  const uint32_t chk1 = (uint32_t)(((4 + ln4) ^ (ln15 & 7)) << 4);
  const uint32_t aBase = (uint32_t)(((wm << 7) + ln15) << 7);   // row = wm*128 + rt*16 + ln15
  const uint32_t bBase = 32768u + (uint32_t)(((wl << 4) + ln15) << 7);
  const uint32_t aK0 = aBase + chk0, aK1 = aBase + chk1;
  const uint32_t bK0 = bBase + chk0, bK1 = bBase + chk1;

#define READS(dstA, dstB, aK, bK, bufB) do {                                            \
    const char* pA_ = smemB + ((aK) + (bufB));                                          \
    const char* pB_ = smemB + ((bK) + (bufB));                                          \
    _Pragma("unroll")                                                                   \
    for (int rt_ = 0; rt_ < 8; ++rt_) dstA[rt_] = *(const bf16x8*)(pA_ + rt_ * 2048);   \
    _Pragma("unroll")                                                                   \
    for (int g_ = 0; g_ < 4; ++g_) dstB[g_] = *(const bf16x8*)(pB_ + g_ * 8192);        \
  } while (0)

#define MFMAS(aset, bset) do {                                                          \
    _Pragma("unroll")                                                                   \
    for (int rt_ = 0; rt_ < 8; ++rt_)                                                   \
      _Pragma("unroll")                                                                 \
      for (int g_ = 0; g_ < 4; ++g_)                                                    \
        acc[rt_][g_] = __builtin_amdgcn_mfma_f32_16x16x32_bf16(                         \
            aset[rt_], bset[g_], acc[rt_][g_], 0, 0, 0);                                \
  } while (0)

#define LGKM0() asm volatile("s_waitcnt lgkmcnt(0)")
#define BAR() __builtin_amdgcn_s_barrier()

  f32x4 acc[8][4];
  #pragma unroll
  for (int i = 0; i < 8; ++i)
    #pragma unroll
    for (int j = 0; j < 4; ++j) {
      f32x4 z = {0.f, 0.f, 0.f, 0.f};
      acc[i][j] = z;
    }

  bf16x8 a0[8], b0[4], a1[8], b1[4];

  // prologue: stage tiles 0,1; load frags(step 0) = tile0 kk0
  STAGE(0, 0);
  STAGE(4096, 1);
  asm volatile("s_waitcnt vmcnt(8)" ::: "memory");  // stage(0) complete
  BAR();
  READS(a0, b0, aK0, bK0, 0u);
  LGKM0();

  #pragma unroll 1
  for (int t = 0; t < NT64; ++t) {
    const uint32_t curB = (uint32_t)(t & 1) << 16;      // byte base of buf(t)
    const uint32_t nxtB = curB ^ 65536u;                // byte base of buf(t+1)
    const int bsCur = (t & 1) << 12;                    // slot base of buf(t)

    // stepA: reads(tile t, kk1) -> set1  ||  MFMA(step 2t) on set0
    READS(a1, b1, aK1, bK1, curB);
    MFMAS(a0, b0);
    LGKM0();                     // set1 frags in regs (hidden under MFMAs)
    BAR();                       // all waves done reading buf(t) from LDS
    if (t + 2 < NT64) STAGE(bsCur, t + 2);   // overwrite buf(t) with tile t+2
    if (t < NT64 - 2) {
      asm volatile("s_waitcnt vmcnt(8)" ::: "memory");  // stage(t+1) complete
    } else {
      asm volatile("s_waitcnt vmcnt(0)" ::: "memory");  // tail: drain all
    }
    BAR();                       // all waves: buf(t+1) ready
    // stepB: reads(tile t+1, kk0) -> set0  ||  MFMA(step 2t+1) on set1
    if (t + 1 < NT64) READS(a0, b0, aK0, bK0, nxtB);
    MFMAS(a1, b1);
    LGKM0();
  }

  // Epilogue (r6/r9-verified): C/D col = lane&15 -> l, row = (lane>>4)*4+j -> n.
  const int l = l0 + (wl << 4) + ln15;
  const float vbi = bi[s * L_ + l];
  const float vbf = bff[s * L_ + l];
  const float vbg = bg[s * L_ + l];
  const float vbo = bo[s * L_ + l];
  #pragma unroll
  for (int rt = 0; rt < 8; ++rt) {
    #pragma unroll
    for (int j = 0; j < 4; ++j) {
      const int n = n0 + (wm << 7) + (rt << 4) + (ln4 << 2) + j;
      const float c0v = c0[(size_t)n * (S_ * L_) + s * L_ + l];
      const float iv = fsigmoid(acc[rt][0][j] + vbi);
      const float fv = fsigmoid(acc[rt][1][j] + vbf);
      const float gv = ftanh(acc[rt][2][j] + vbg);
      const float ov = fsigmoid(acc[rt][3][j] + vbo);
      const float cn = fv * c0v + iv * gv;
      const float hn = ov * ftanh(cn);
      hout[(size_t)(s * N_ + n) * L_ + l] = f2bf(hn);
    }
  }
#undef STAGE
#undef READS
#undef MFMAS
#undef LGKM0
#undef BAR
}

// ---------------- output GEMM (verified r1-r16) ----------------
__global__ __launch_bounds__(256, 2) void out_kernel(
    const ushort_t* __restrict__ h,    // [S][N][L] bf16
    const ushort_t* __restrict__ wy,   // [S][M][L] bf16
    const float* __restrict__ by,      // [S*M]
    float* __restrict__ out)           // [N][S*M]
{
  __shared__ __align__(16) ushort_t smem[1536 * 8];
  const int tid = threadIdx.x;
  const int lane = tid & 63;
  const int w = tid >> 6;
  const int n0 = blockIdx.x * 128;
  const int m0 = blockIdx.y * 64;
  const int s = blockIdx.z;

  f32x4 acc[2][4];
  #pragma unroll
  for (int rt = 0; rt < 2; ++rt)
    #pragma unroll
    for (int ct = 0; ct < 4; ++ct) {
      f32x4 z = {0.f, 0.f, 0.f, 0.f};
      acc[rt][ct] = z;
    }

  const size_t h_row0 = (size_t)(s * N_ + n0) * L_;

  for (int t = 0; t < L_ / 64; ++t) {
    const int k0 = t * 64;
    #pragma unroll
    for (int it = 0; it < 4; ++it) {
      int chunk = it * 256 + tid;
      int rr = chunk >> 3, c = chunk & 7;
      int cg = c ^ (rr & 7);
      const ushort_t* src = h + h_row0 + (size_t)rr * L_ + k0 + cg * 8;
      GLD16(src, &smem[(it * 256 + w * 64) * 8]);
    }
    #pragma unroll
    for (int it = 0; it < 2; ++it) {
      int chunk = it * 256 + tid;
      int rl = chunk >> 3, c = chunk & 7;
      int cg = c ^ (rl & 7);
      const ushort_t* src = wy + ((size_t)(s * M_ + m0 + rl)) * L_ + k0 + cg * 8;
      GLD16(src, &smem[(1024 + it * 256 + w * 64) * 8]);
    }
    __syncthreads();
    #pragma unroll
    for (int kk = 0; kk < 2; ++kk) {
      const int cc = kk * 4 + (lane >> 4);
      bf16x8 av[2];
      #pragma unroll
      for (int rt = 0; rt < 2; ++rt) {
        int rr = w * 32 + rt * 16 + (lane & 15);
        av[rt] = *(const bf16x8*)&smem[(rr * 8 + (cc ^ (rr & 7))) * 8];
      }
      #pragma unroll
      for (int ct = 0; ct < 4; ++ct) {
        int rl = ct * 16 + (lane & 15);
        bf16x8 b = *(const bf16x8*)&smem[(1024 + rl * 8 + (cc ^ (rl & 7))) * 8];
        acc[0][ct] = __builtin_amdgcn_mfma_f32_16x16x32_bf16(av[0], b, acc[0][ct], 0, 0, 0);
        acc[1][ct] = __builtin_amdgcn_mfma_f32_16x16x32_bf16(av[1], b, acc[1][ct], 0, 0, 0);
      }
    }
    __syncthreads();
  }

  #pragma unroll
  for (int ct = 0; ct < 4; ++ct) {
    const int m = m0 + ct * 16 + (lane & 15);
    const float vb = by[s * M_ + m];
    #pragma unroll
    for (int rt = 0; rt < 2; ++rt) {
      #pragma unroll
      for (int j = 0; j < 4; ++j) {
        const int n = n0 + w * 32 + rt * 16 + (lane >> 4) * 4 + j;
        out[(size_t)n * (S_ * M_) + s * M_ + m] = acc[rt][ct][j] + vb;
      }
    }
  }
}

// ---------------- launcher ----------------

extern "C" void kernel_launch(void* const* d_in, const int* in_sizes, int n_in,
                              void* d_out, int out_size, void* d_ws, size_t ws_size,
                              hipStream_t stream) {
  const float* mod = (const float*)d_in[0];
  const float* h0  = (const float*)d_in[1];
  const float* c0  = (const float*)d_in[2];
  const float* Wi  = (const float*)d_in[3];
  const float* bi  = (const float*)d_in[4];
  const float* Wf  = (const float*)d_in[5];
  const float* bf  = (const float*)d_in[6];
  const float* Wg  = (const float*)d_in[7];
  const float* bg  = (const float*)d_in[8];
  const float* Wo  = (const float*)d_in[9];
  const float* bo  = (const float*)d_in[10];
  const float* Wy  = (const float*)d_in[11];
  const float* by  = (const float*)d_in[12];
  float* out = (float*)d_out;

  ushort_t* ws = (ushort_t*)d_ws;
  ushort_t* xh   = ws;
  ushort_t* w4   = xh  + (size_t)S_ * N_ * D_;
  ushort_t* wyb  = w4  + (size_t)4 * S_ * L_ * D_;
  ushort_t* hbuf = wyb + (size_t)S_ * M_ * L_;

  prep_kernel<<<dim3(768, 7), 256, 0, stream>>>(mod, h0, Wi, Wf, Wg, Wo, Wy, w4, wyb, xh);
  gates_kernel<<<1024, 512, 0, stream>>>(xh, w4, bi, bf, bg, bo, c0, hbuf);
  out_kernel<<<dim3(N_ / 128, M_ / 64, S_), 256, 0, stream>>>(hbuf, wyb, by, out);
}